// Round 4
// baseline (335.064 us; speedup 1.0000x reference)
//
#include <hip/hip_runtime.h>
#include <math.h>

#define NT      256
#define FFT_N   1024
#define LOG2N   10
#define ROW_IN  2560      // 2*(FFT_SIZE+CP_LEN) floats
#define NSYMS   824
#define ROW_OUT 1648      // 2*NSYMS floats
#define NPILOT  9

// f32(2*pi/1024): exact value of numpy's float32 ramp constant
#define C32_TWOPI_1024  6.1359233222901821136474609375e-3f

__global__ __launch_bounds__(NT) void ofdm_kernel(const float* __restrict__ in,
                                                  float* __restrict__ out) {
    __shared__ double2 bufA[FFT_N];
    __shared__ double2 bufB[FFT_N];
    __shared__ double2 twl[FFT_N / 2];
    __shared__ double  ang[NPILOT];

    const int row = blockIdx.x;        // b*1024 + r
    const int tid = threadIdx.x;

    // ---- load 1024 complex samples at complex offset 128 (CP/2), f32 -> f64 ----
    const float2* rin2 = (const float2*)(in + (size_t)row * ROW_IN) + 128;
    #pragma unroll
    for (int j = 0; j < 4; j++) {
        int k = tid + j * NT;
        float2 v = rin2[k];
        bufA[k] = make_double2((double)v.x, (double)v.y);
    }

    // ---- twiddles: twl[k] = exp(-2*pi*i*k/1024), k in [0,512), f64 ----
    #pragma unroll
    for (int j = 0; j < 2; j++) {
        int k = tid + j * NT;
        double sn, cs;
        sincos((double)k * -6.1359231515425649189e-3, &sn, &cs);  // -2pi/1024
        twl[k] = make_double2(cs, sn);
    }
    __syncthreads();

    // ---- Stockham radix-2 DIF, ping-pong, natural-order output ----
    double2* src = bufA;
    double2* dst = bufB;
    #pragma unroll
    for (int stage = 0; stage < LOG2N; stage++) {
        const int s = 1 << stage;
        #pragma unroll
        for (int j = 0; j < 2; j++) {
            const int i = tid + j * NT;              // 0..511
            double2 a = src[i];
            double2 b = src[i + 512];
            double2 w = twl[i & ~(s - 1)];
            int j0 = ((i >> stage) << (stage + 1)) | (i & (s - 1));
            double2 d1 = make_double2(a.x - b.x, a.y - b.y);
            dst[j0]     = make_double2(a.x + b.x, a.y + b.y);
            dst[j0 + s] = make_double2(d1.x * w.x - d1.y * w.y,
                                       d1.x * w.y + d1.y * w.x);
        }
        double2* t = src; src = dst; dst = t;
        __syncthreads();
    }
    // X[k] in src[k]; result[j] = X[j^512] * exp(i*theta32(j)),
    // theta32(j) = f32(f32(128*j) * f32(2pi/1024))  (numpy complex64 ramp)

    // ---- pilot angles (9 threads write; bit-exact f32 ramp emulation) ----
    if (tid < NPILOT) {
        int jj = 95 + tid * 100;
        double2 v = src[jj ^ 512];
        float th32 = (float)(128 * jj) * C32_TWOPI_1024;   // single f32 multiply
        double sn, cs;
        sincos((double)th32, &sn, &cs);
        double csf = (double)(float)cs;    // complex64 ramp components
        double snf = (double)(float)sn;
        double re = v.x * csf - v.y * snf;
        double im = v.x * snf + v.y * csf;
        ang[tid] = atan2(im, re);
    }
    __syncthreads();

    // ---- every thread independently computes the wrapped-diff mean ----
    double a0 = ang[0], a1 = ang[1], a2 = ang[2], a3 = ang[3], a4 = ang[4];
    double a5 = ang[5], a6 = ang[6], a7 = ang[7], a8 = ang[8];
    double mn;
    {
        double diffs[8] = { a1 - a0, a2 - a1, a3 - a2, a4 - a3,
                            a5 - a4, a6 - a5, a7 - a6, a8 - a7 };
        double sum = 0.0;
        #pragma unroll
        for (int i = 0; i < 8; i++) {
            double a = diffs[i];
            if (a > 3.14159265358979323846)       a -= 6.28318530717958647693;
            else if (a < -3.14159265358979323846) a += 6.28318530717958647693;
            sum += a;
        }
        mn = sum * 0.125;
    }

    // ---- correction + gather: DATA_IDX[d] = 96 + d + d/99 ----
    // phase = theta32(jj) - mn*jj/100   (combined rotor, f64 sincos)
    float2* rout = (float2*)(out + (size_t)row * ROW_OUT);
    #pragma unroll
    for (int jl = 0; jl < 4; jl++) {
        int d = tid + jl * NT;
        if (d < NSYMS) {
            int jj = 96 + d + d / 99;
            double2 v = src[jj ^ 512];
            float th32 = (float)(128 * jj) * C32_TWOPI_1024;
            double ph = (double)th32 - mn * 0.01 * (double)jj;
            double sn, cs;
            sincos(ph, &sn, &cs);
            double re = v.x * cs - v.y * sn;
            double im = v.x * sn + v.y * cs;
            rout[d] = make_float2((float)re, (float)im);
        }
    }
}

extern "C" void kernel_launch(void* const* d_in, const int* in_sizes, int n_in,
                              void* d_out, int out_size, void* d_ws, size_t ws_size,
                              hipStream_t stream) {
    const float* in = (const float*)d_in[0];
    float* out = (float*)d_out;
    ofdm_kernel<<<dim3(16 * 1024), dim3(NT), 0, stream>>>(in, out);
}

// Round 5
// 319.986 us; speedup vs baseline: 1.0471x; 1.0471x over previous
//
#include <hip/hip_runtime.h>
#include <math.h>

#define NT      256
#define NSYMS   824
#define NPILOT  9

// padded LDS index: +1 element per 16 to break power-of-2 bank strides
#define PADIDX(k) ((k) + ((k) >> 4))

// f32(2*pi/1024): exact value of numpy's float32 ramp constant
#define C32_TWOPI_1024  6.1359233222901821136474609375e-3f

__device__ __forceinline__ float2 cmulf(float2 a, float2 b) {
    return make_float2(a.x * b.x - a.y * b.y, a.x * b.y + a.y * b.x);
}

// one radix-4 Stockham DIF stage; T2 = 2*t, s = 4^t = 1<<T2
template <int T2>
__device__ __forceinline__ void r4_stage(const float2* __restrict__ src,
                                         float2* __restrict__ dst,
                                         const float2* __restrict__ W,
                                         int i) {
    const int s = 1 << T2;
    const int r = i & (s - 1);
    const int p = i & ~(s - 1);            // twiddle base exponent (multiple of s)
    const int pb = PADIDX(i);
    float2 a = src[pb];
    float2 b = src[pb + 272];              // PADIDX(i+256) = PADIDX(i)+272
    float2 c = src[pb + 544];
    float2 d = src[pb + 816];
    float2 w1 = W[PADIDX(p)];
    float2 w2 = W[PADIDX(2 * p)];
    float2 w3 = W[PADIDX(3 * p)];
    float2 t0  = make_float2(a.x + c.x, a.y + c.y);
    float2 t1  = make_float2(a.x - c.x, a.y - c.y);
    float2 t2c = make_float2(b.x + d.x, b.y + d.y);
    float2 t3  = make_float2(b.x - d.x, b.y - d.y);
    float2 y0  = make_float2(t0.x + t2c.x, t0.y + t2c.y);
    float2 e1  = make_float2(t1.x + t3.y, t1.y - t3.x);   // t1 - i*t3
    float2 e2  = make_float2(t0.x - t2c.x, t0.y - t2c.y);
    float2 e3  = make_float2(t1.x - t3.y, t1.y + t3.x);   // t1 + i*t3
    const int j0 = ((i >> T2) << (T2 + 2)) | r;
    dst[PADIDX(j0)]         = y0;
    dst[PADIDX(j0 + s)]     = cmulf(w1, e1);
    dst[PADIDX(j0 + 2 * s)] = cmulf(w2, e2);
    dst[PADIDX(j0 + 3 * s)] = cmulf(w3, e3);
}

__global__ __launch_bounds__(NT) void ofdm_kernel(const float* __restrict__ in,
                                                  float* __restrict__ out) {
    __shared__ float2  bufA[1088];
    __shared__ float2  bufB[1088];
    __shared__ float2  W[1088];       // f32 twiddles  w^k = exp(-2*pi*i*k/1024)
    __shared__ double2 T[1088];       // f64 twiddles (pilot path)
    __shared__ double2 u_s[NT];       // radix-4 folded input for pilot DFT
    __shared__ double2 pr[252];       // pilot partial sums
    __shared__ double  ang[NPILOT];

    const int row = blockIdx.x;       // 0..16383
    const int tid = threadIdx.x;

    // ---- load 1024 complex samples at complex offset 128 (CP/2) ----
    const float2* rin2 = (const float2*)(in + (size_t)row * 2560) + 128;
    float2 v0 = rin2[tid];
    float2 v1 = rin2[tid + 256];
    float2 v2 = rin2[tid + 512];
    float2 v3 = rin2[tid + 768];

    // ---- pilot fold (f64): u_t = x_t + i*x_{t+256} - x_{t+512} - i*x_{t+768}
    // valid because pilot FFT bins K = (jj+512)&1023 satisfy K mod 4 == 3,
    // so w^{256*K*delta} = i^delta.
    double ux = ((double)v0.x - (double)v2.x) - ((double)v1.y - (double)v3.y);
    double uy = ((double)v0.y - (double)v2.y) + ((double)v1.x - (double)v3.x);

    // ---- twiddle tables: 1 f64 sincos/thread + quadrant symmetry ----
    {
        double sn, cs;
        sincos((double)tid * -6.1359231515425649189e-3, &sn, &cs);  // -2pi/1024
        T[PADIDX(tid)]       = make_double2(cs, sn);
        T[PADIDX(tid + 256)] = make_double2(sn, -cs);    // *(-i)
        T[PADIDX(tid + 512)] = make_double2(-cs, -sn);   // *(-1)
        T[PADIDX(tid + 768)] = make_double2(-sn, cs);    // *(i)
        float cf = (float)cs, sf = (float)sn;
        W[PADIDX(tid)]       = make_float2(cf, sf);
        W[PADIDX(tid + 256)] = make_float2(sf, -cf);
        W[PADIDX(tid + 512)] = make_float2(-cf, -sf);
        W[PADIDX(tid + 768)] = make_float2(-sf, cf);
    }

    bufA[PADIDX(tid)]       = v0;
    bufA[PADIDX(tid + 256)] = v1;
    bufA[PADIDX(tid + 512)] = v2;
    bufA[PADIDX(tid + 768)] = v3;
    u_s[tid] = make_double2(ux, uy);
    __syncthreads();

    // ---- pilot partials: bin p handled by 28 threads, ~10 terms each ----
    if (tid < 252) {
        int p = tid / 28;
        int g = tid - p * 28;
        int t0s = 10 * g;
        double2 acc = make_double2(0.0, 0.0);
        int nmax = 256 - t0s; if (nmax > 10) nmax = 10;
        if (nmax > 0) {
            int jj = 95 + 100 * p;
            int K = (jj + 512) & 1023;          // rolled FFT bin
            int idx = (K * t0s) & 1023;
            for (int m = 0; m < nmax; m++) {
                double2 w = T[PADIDX(idx)];
                double2 uu = u_s[t0s + m];
                acc.x += w.x * uu.x - w.y * uu.y;
                acc.y += w.x * uu.y + w.y * uu.x;
                idx = (idx + K) & 1023;
            }
        }
        pr[tid] = acc;
    }
    // ---- FFT stage 0 (A->B) in the same phase ----
    r4_stage<0>(bufA, bufB, W, tid);
    __syncthreads();

    // ---- finalize pilots on 9 threads (overlapped with stage 1) ----
    if (tid < NPILOT) {
        double2 ssum = make_double2(0.0, 0.0);
        #pragma unroll
        for (int g = 0; g < 28; g++) {
            double2 q = pr[tid * 28 + g];
            ssum.x += q.x; ssum.y += q.y;
        }
        int jj = 95 + 100 * tid;
        // bit-exact emulation of numpy's complex64 ramp (round-4 formula)
        float th32 = (float)(128 * jj) * C32_TWOPI_1024;
        double sn, cs;
        sincos((double)th32, &sn, &cs);
        double csf = (double)(float)cs;
        double snf = (double)(float)sn;
        double re = ssum.x * csf - ssum.y * snf;
        double im = ssum.x * snf + ssum.y * csf;
        ang[tid] = atan2(im, re);
    }
    r4_stage<2>(bufB, bufA, W, tid);
    __syncthreads();
    r4_stage<4>(bufA, bufB, W, tid);
    __syncthreads();
    r4_stage<6>(bufB, bufA, W, tid);
    __syncthreads();
    r4_stage<8>(bufA, bufB, W, tid);          // final result in bufB
    __syncthreads();

    // ---- wrapped-diff mean (every thread, f64, same as round 4) ----
    double mn;
    {
        double sum = 0.0;
        double prev = ang[0];
        #pragma unroll
        for (int k = 1; k < NPILOT; k++) {
            double cur = ang[k];
            double a = cur - prev;
            if (a > 3.14159265358979323846)       a -= 6.28318530717958647693;
            else if (a < -3.14159265358979323846) a += 6.28318530717958647693;
            sum += a;
            prev = cur;
        }
        mn = sum * 0.125;
    }

    // ---- correction + gather: DATA_IDX[d] = 96 + d + d/99 ----
    float2* rout = (float2*)(out + (size_t)row * (2 * NSYMS));
    #pragma unroll
    for (int jl = 0; jl < 4; jl++) {
        int d = tid + jl * NT;
        if (d < NSYMS) {
            int jj = 96 + d + d / 99;
            float2 z = bufB[PADIDX(jj ^ 512)];
            float th32 = (float)(128 * jj) * C32_TWOPI_1024;
            float ph = th32 - (float)(mn * 0.01 * (double)jj);
            float sn, cs;
            __sincosf(ph, &sn, &cs);
            rout[d] = make_float2(z.x * cs - z.y * sn,
                                  z.x * sn + z.y * cs);
        }
    }
}

extern "C" void kernel_launch(void* const* d_in, const int* in_sizes, int n_in,
                              void* d_out, int out_size, void* d_ws, size_t ws_size,
                              hipStream_t stream) {
    const float* in = (const float*)d_in[0];
    float* out = (float*)d_out;
    ofdm_kernel<<<dim3(16 * 1024), dim3(NT), 0, stream>>>(in, out);
}